// Round 14
// baseline (168.992 us; speedup 1.0000x reference)
//
#include <hip/hip_runtime.h>
#include <hip/hip_bf16.h>

#define NDIM 128
#define N2   (NDIM * NDIM)
#define BDIM 131072
#define NMZI 8128                       // 128*127/2
#define NBLK 32                         // build_all grid; 8 build blocks + all join compose
#define SPLIT 56                        // chunk A = sweeps [0,56), chunk B = [56,128)
#define NJG 8                           // j-groups per block (scan groups)
#define NCOL 32                         // columns per block
#define NLOC 16                         // max local scan length = ceil(127/8)
static constexpr float CC = 0.70710678118654752440f;  // sqrt(0.5)

typedef __attribute__((ext_vector_type(8))) short bf16x8;
typedef __attribute__((ext_vector_type(4))) float f32x4;

// Static device scratch (d_ws size unknown -> don't touch it)
__device__ __align__(16) float2         g_V[2 * N2];        // chunk partial unitaries
// Packed K=256 table for real-output GEMM: kg2<16 -> Ur[k=kg2*8+e][n]; kg2>=16 -> -Ui
__device__ __align__(16) unsigned short g_TB[32 * NDIM * 8];        // 64 KB
// Separate tables for the (unlikely) complex-interleaved output mode
__device__ __align__(16) unsigned short g_Ur[16 * NDIM * 8];
__device__ __align__(16) unsigned short g_Ui[16 * NDIM * 8];
// grid-barrier counter (monotonic within build_all; reset ATOMICALLY by the
// following cmatmul launch — never mid-kernel, so no spin/reset race)
__device__ unsigned g_ctr[3];

__device__ inline unsigned short f2bf(float f) {
    union { __hip_bfloat16 h; unsigned short u; } cv;
    cv.h = __float2bfloat16(f);
    return cv.u;
}

// ---- device-scope grid barrier: RELAXED spin (no per-poll cache invalidate) ----
__device__ __forceinline__ void gbar0() {
    __syncthreads();
    asm volatile("" ::: "memory");
    if (threadIdx.x == 0) {
        __threadfence();   // release: my g_V writes reach device scope
        __hip_atomic_fetch_add(&g_ctr[0], 1u, __ATOMIC_RELEASE, __HIP_MEMORY_SCOPE_AGENT);
        while (__hip_atomic_load(&g_ctr[0], __ATOMIC_RELAXED, __HIP_MEMORY_SCOPE_AGENT)
               < (unsigned)NBLK)
            __builtin_amdgcn_s_sleep(2);
        __threadfence();   // acquire ONCE after exit: invalidate stale lines
    }
    __syncthreads();
    asm volatile("" ::: "memory");
}

#define CFMA(acc, av, b)                                                    \
    acc.x = fmaf(av.x, b.x, fmaf(-av.y, b.y, acc.x));                       \
    acc.y = fmaf(av.x, b.y, fmaf( av.y, b.x, acc.y));

// ---------------- K1: build 2 chunk unitaries + final product, ONE kernel ----------
// 32 blocks x 256 threads. Blocks 0..7 (4 col-slabs x 2 chunks) run the
// sweep-aligned affine-scan (R10-verified body); blocks 8..31 go straight
// to the barrier. After ONE gbar, all 32 blocks compute U = V1*V0 (4 rows
// each, R12-verified pipelined unit), apply diag, pack bf16 tables.
__global__ __launch_bounds__(256) void build_all(const float* __restrict__ mzi,
                                                 const float* __restrict__ oph) {
    __shared__ __align__(16) char SM[40960];
    const int tid = threadIdx.x;
    const int b   = blockIdx.x;

    if (b < 8) {
        // ---- phase A: build chunk partial unitary ----
        float2 (*Usm)[NCOL] = reinterpret_cast<float2(*)[NCOL]>(SM);          // 32 KB
        float4 (*ph)[NDIM]  = reinterpret_cast<float4(*)[NDIM]>(SM + 32768);  // 4 KB
        float4 (*cmp)[NCOL] = reinterpret_cast<float4(*)[NCOL]>(SM + 36864);  // 4 KB
        const int c     = tid & 31;
        const int g     = tid >> 5;
        const int col0  = (b & 3) * NCOL;
        const int chunk = b >> 2;                 // 0 or 1
        const int i0    = chunk ? SPLIT : 0;
        const int iEnd  = chunk ? (NDIM - 1) : SPLIT;   // sweeps [i0, iEnd)
        const int nsw   = iEnd - i0;

        for (int k = g; k < NDIM; k += NJG)
            Usm[k][c] = make_float2((k == col0 + c) ? 1.f : 0.f, 0.f);

        const float2* mzp = (const float2*)mzi;   // (theta, phi) pairs
        int base = 127 * i0 - (i0 * (i0 - 1)) / 2;
        {
            const int L0 = NDIM - 1 - i0;
            if (tid < L0) {
                const float2 mz = mzp[base + tid];
                float sp, cp, st, ct;
                sincosf(mz.y, &sp, &cp);
                sincosf(mz.x, &st, &ct);
                ph[0][tid] = make_float4(cp, sp, CC * ct, CC * st);
            }
        }
        __syncthreads();

        #pragma unroll 1
        for (int sw = 0; sw < nsw; ++sw) {
            const int i = i0 + sw;
            const int L = NDIM - 1 - i;           // sweep length (>=1)
            const int cur = sw & 1;

            float2 mznext;
            const bool have = (sw < nsw - 1) && (tid < L - 1);
            if (have) mznext = mzp[base + L + tid];

            const float2 r0 = Usm[i][c];          // read BEFORE barrier
            const int nloc  = (L + NJG - 1) >> 3;
            const int myBeg = g * nloc;
            const int myN   = max(0, min(nloc, L - myBeg));

            float2 treg[NLOC];
            float2 qth[NLOC];
            float  A = 1.f;
            float2 Bc = make_float2(0.f, 0.f);
            #pragma unroll
            for (int kk = 0; kk < NLOC; ++kk) {
                if (kk < myN) {
                    const int off = myBeg + kk;
                    const float4 q  = ph[cur][off];
                    const float2 rj = Usm[i + 1 + off][c];
                    const float tr = fmaf(q.x, rj.x, -q.y * rj.y);
                    const float ti = fmaf(q.x, rj.y,  q.y * rj.x);
                    treg[kk] = make_float2(tr, ti);
                    qth[kk]  = make_float2(q.z, q.w);
                    Bc.x = CC * (Bc.x + tr);
                    Bc.y = CC * (Bc.y + ti);
                    A *= CC;
                }
            }
            cmp[g][c] = make_float4(A, Bc.x, Bc.y, 0.f);
            __syncthreads();

            float2 r = r0;
            for (int h2 = 0; h2 < g; ++h2) {
                const float4 cm = cmp[h2][c];
                r.x = fmaf(cm.x, r.x, cm.y);
                r.y = fmaf(cm.x, r.y, cm.z);
            }

            #pragma unroll
            for (int kk = 0; kk < NLOC; ++kk) {
                if (kk < myN) {
                    const float2 t = treg[kk];
                    const float2 q = qth[kk];
                    const float dr = r.x - t.x, di = r.y - t.y;
                    const float njx = fmaf(q.x, dr, -q.y * di);
                    const float njy = fmaf(q.x, di,  q.y * dr);
                    Usm[i + 1 + myBeg + kk][c] = make_float2(njx, njy);
                    r.x = CC * (r.x + t.x);
                    r.y = CC * (r.y + t.y);
                }
            }
            if (myN > 0 && (myBeg + myN == L))
                Usm[i][c] = r;

            if (have) {
                float sp, cp, st, ct;
                sincosf(mznext.y, &sp, &cp);
                sincosf(mznext.x, &st, &ct);
                ph[cur ^ 1][tid] = make_float4(cp, sp, CC * ct, CC * st);
            }
            __syncthreads();
            base += L;
        }

        float2* Vp = g_V + chunk * N2;
        for (int k = g; k < NDIM; k += NJG)
            Vp[k * NDIM + col0 + c] = Usm[k][c];
    }

    gbar0();   // ONE barrier: both g_V chunks visible device-wide

    // ---- phase B: final U = V1*V0 (+diag, pack), 4 rows per block ----
    {
        const int h  = tid >> 7;                  // block half (h==0 active)
        const int m  = tid & 127;
        const int n0 = b * 4;
        float2* As = (float2*)SM;                 // 4 KB
        const float2* A = g_V + N2;               // V1 (left)
        const float2* B = g_V;                    // V0 (right; +8-row overrun lands in V1: safe)

        __syncthreads();
        if (h == 0) {
            #pragma unroll
            for (int r = 0; r < 4; ++r) As[r * NDIM + m] = A[(n0 + r) * NDIM + m];
        }
        __syncthreads();
        if (h == 0) {
            float2 a0 = {0.f, 0.f}, a1 = {0.f, 0.f}, a2 = {0.f, 0.f}, a3 = {0.f, 0.f};
            float2 bb[8];
            #pragma unroll
            for (int u = 0; u < 8; ++u) bb[u] = B[u * NDIM + m];

            #pragma unroll 1
            for (int k0 = 0; k0 < NDIM; k0 += 8) {
                #pragma unroll
                for (int u = 0; u < 8; ++u) {
                    const float2 bv = bb[u];
                    bb[u] = B[(k0 + 8 + u) * NDIM + m];   // last-iter overrun: safe
                    const int k = k0 + u;
                    float2 v;
                    v = As[0 * NDIM + k]; CFMA(a0, v, bv)
                    v = As[1 * NDIM + k]; CFMA(a1, v, bv)
                    v = As[2 * NDIM + k]; CFMA(a2, v, bv)
                    v = As[3 * NDIM + k]; CFMA(a3, v, bv)
                }
            }
            const int kg = m >> 3, e = m & 7;
            #pragma unroll
            for (int r = 0; r < 4; ++r) {
                const int n = n0 + r;
                const float2 u = (r == 0) ? a0 : (r == 1) ? a1 : (r == 2) ? a2 : a3;
                float ds, dc;
                sincosf(oph[n], &ds, &dc);
                const float vr = fmaf(u.x, dc, -u.y * ds);
                const float vi = fmaf(u.x, ds,  u.y * dc);
                g_TB[(kg * NDIM + n) * 8 + e]        = f2bf(vr);
                g_TB[((16 + kg) * NDIM + n) * 8 + e] = f2bf(-vi);
                g_Ur[(kg * NDIM + n) * 8 + e] = f2bf(vr);
                g_Ui[(kg * NDIM + n) * 8 + e] = f2bf(vi);
            }
        }
    }
}

// ---------------- K2a: real-output GEMM (R10-verified, 49.3 us) ----------------
__global__ __launch_bounds__(256) void cmatmul0(const float* __restrict__ xr,
                                                const float* __restrict__ xi,
                                                float* __restrict__ out) {
    if (blockIdx.x == 0 && threadIdx.x == 0) {    // reset barrier counters at
        #pragma unroll                            // device scope (visible to
        for (int i = 0; i < 3; ++i)               // next replay's atomics)
            __hip_atomic_store(&g_ctr[i], 0u, __ATOMIC_RELAXED, __HIP_MEMORY_SCOPE_AGENT);
    }
    __shared__ __align__(16) char smX[4][8192];   // per-wave tile buffer
    const int tid  = threadIdx.x;
    const int lane = tid & 63;
    const int w    = tid >> 6;
    const int r15  = lane & 15;
    const int kg4  = lane >> 4;
    const int l31  = lane & 31;
    const int lh   = lane >> 5;
    const int R    = blockIdx.x * 64 + w * 16;    // wave's tile base row

    const f32x4* sre = (const f32x4*)(xr + (size_t)R * NDIM);
    const f32x4* sim = (const f32x4*)(xi + (size_t)R * NDIM);
    f32x4 G[16];
    #pragma unroll
    for (int p = 0; p < 8; ++p) G[p]     = __builtin_nontemporal_load(sre + p * 64 + lane);
    #pragma unroll
    for (int p = 0; p < 8; ++p) G[8 + p] = __builtin_nontemporal_load(sim + p * 64 + lane);

    char* buf = &smX[w][0];
    #pragma unroll
    for (int p = 0; p < 8; ++p) {
        const int row = 2 * p + lh;
        const int swz = (row & 7) << 4;
        uint2 v;
        v.x = ((unsigned)f2bf(G[p][1]) << 16) | f2bf(G[p][0]);
        v.y = ((unsigned)f2bf(G[p][3]) << 16) | f2bf(G[p][2]);
        *(uint2*)(buf + row * 512 + ((l31 * 8) ^ swz)) = v;
        v.x = ((unsigned)f2bf(G[8 + p][1]) << 16) | f2bf(G[8 + p][0]);
        v.y = ((unsigned)f2bf(G[8 + p][3]) << 16) | f2bf(G[8 + p][2]);
        *(uint2*)(buf + row * 512 + 256 + ((l31 * 8) ^ swz)) = v;
    }

    bf16x8 fx[8];
    const int rswz = (r15 & 7) << 4;
    #pragma unroll
    for (int kc = 0; kc < 8; ++kc) {
        const int off = (((kc & 3) * 64 + kg4 * 16) ^ rswz) + ((kc >= 4) ? 256 : 0);
        fx[kc] = *(const bf16x8*)(buf + r15 * 512 + off);
    }

    const bf16x8* gT = (const bf16x8*)g_TB;
    #pragma unroll
    for (int nt = 0; nt < 8; ++nt) {
        f32x4 a0 = {0.f, 0.f, 0.f, 0.f};
        f32x4 a1 = {0.f, 0.f, 0.f, 0.f};
        #pragma unroll
        for (int kc = 0; kc < 4; ++kc)
            a0 = __builtin_amdgcn_mfma_f32_16x16x32_bf16(
                gT[(kc * 4 + kg4) * NDIM + nt * 16 + r15], fx[kc], a0, 0, 0, 0);
        #pragma unroll
        for (int kc = 4; kc < 8; ++kc)
            a1 = __builtin_amdgcn_mfma_f32_16x16x32_bf16(
                gT[(kc * 4 + kg4) * NDIM + nt * 16 + r15], fx[kc], a1, 0, 0, 0);
        const f32x4 s = a0 + a1;
        *(f32x4*)(buf + r15 * 512 + ((nt * 64 + kg4 * 16) ^ rswz)) = s;
    }

    char* outp = (char*)(out + (size_t)R * NDIM);
    #pragma unroll
    for (int p = 0; p < 8; ++p) {
        const int bofs = p * 1024 + lane * 16;
        const int row  = bofs >> 9;
        const int colb = bofs & 511;
        const f32x4 v = *(const f32x4*)(buf + row * 512 + (colb ^ ((row & 7) << 4)));
        __builtin_nontemporal_store(v, (f32x4*)(outp + bofs));
    }
}

// ---------------- K2b: complex-output fallback (bf16 re,im pairs) ----------------
__global__ __launch_bounds__(256) void cmatmul1(const float* __restrict__ xr,
                                                const float* __restrict__ xi,
                                                ushort2* __restrict__ outp) {
    if (blockIdx.x == 0 && threadIdx.x == 0) {
        #pragma unroll
        for (int i = 0; i < 3; ++i)
            __hip_atomic_store(&g_ctr[i], 0u, __ATOMIC_RELAXED, __HIP_MEMORY_SCOPE_AGENT);
    }
    const int lane  = threadIdx.x & 63;
    const int w     = threadIdx.x >> 6;
    const int btile = blockIdx.x * 64 + w * 16;
    const int r15   = lane & 15;
    const int kg4   = lane >> 4;
    const int bload = btile + r15;

    const bf16x8* Ur = (const bf16x8*)g_Ur;
    const bf16x8* Ui = (const bf16x8*)g_Ui;
    const float* xrp = xr + (size_t)bload * NDIM;
    const float* xip = xi + (size_t)bload * NDIM;

    bf16x8 ar[4], ai[4], ain[4];
    #pragma unroll
    for (int kc = 0; kc < 4; ++kc) {
        const int k0 = kc * 32 + kg4 * 8;
        float4 rlo = *(const float4*)(xrp + k0);
        float4 rhi = *(const float4*)(xrp + k0 + 4);
        float4 ilo = *(const float4*)(xip + k0);
        float4 ihi = *(const float4*)(xip + k0 + 4);
        bf16x8 vr, vi, vn;
        vr[0] = (short)f2bf(rlo.x); vr[1] = (short)f2bf(rlo.y);
        vr[2] = (short)f2bf(rlo.z); vr[3] = (short)f2bf(rlo.w);
        vr[4] = (short)f2bf(rhi.x); vr[5] = (short)f2bf(rhi.y);
        vr[6] = (short)f2bf(rhi.z); vr[7] = (short)f2bf(rhi.w);
        vi[0] = (short)f2bf(ilo.x); vi[1] = (short)f2bf(ilo.y);
        vi[2] = (short)f2bf(ilo.z); vi[3] = (short)f2bf(ilo.w);
        vi[4] = (short)f2bf(ihi.x); vi[5] = (short)f2bf(ihi.y);
        vi[6] = (short)f2bf(ihi.z); vi[7] = (short)f2bf(ihi.w);
        #pragma unroll
        for (int e = 0; e < 8; ++e) vn[e] = (short)(vi[e] ^ 0x8000);
        ar[kc] = vr; ai[kc] = vi; ain[kc] = vn;
    }

    #pragma unroll
    for (int nt = 0; nt < 8; ++nt) {
        f32x4 accR = {0.f, 0.f, 0.f, 0.f};
        f32x4 accI = {0.f, 0.f, 0.f, 0.f};
        #pragma unroll
        for (int kc = 0; kc < 4; ++kc) {
            const int kg = kc * 4 + kg4;
            bf16x8 br = Ur[kg * NDIM + nt * 16 + r15];
            bf16x8 bi = Ui[kg * NDIM + nt * 16 + r15];
            accR = __builtin_amdgcn_mfma_f32_16x16x32_bf16(ar[kc],  br, accR, 0, 0, 0);
            accR = __builtin_amdgcn_mfma_f32_16x16x32_bf16(ain[kc], bi, accR, 0, 0, 0);
            accI = __builtin_amdgcn_mfma_f32_16x16x32_bf16(ar[kc],  bi, accI, 0, 0, 0);
            accI = __builtin_amdgcn_mfma_f32_16x16x32_bf16(ai[kc],  br, accI, 0, 0, 0);
        }
        const int n    = nt * 16 + r15;
        const int brow = btile + kg4 * 4;
        #pragma unroll
        for (int r = 0; r < 4; ++r)
            outp[(size_t)(brow + r) * NDIM + n] = make_ushort2(f2bf(accR[r]), f2bf(accI[r]));
    }
}

extern "C" void kernel_launch(void* const* d_in, const int* in_sizes, int n_in,
                              void* d_out, int out_size, void* d_ws, size_t ws_size,
                              hipStream_t stream) {
    const float* xr  = (const float*)d_in[0];
    const float* xi  = (const float*)d_in[1];
    const float* mzi = (const float*)d_in[2];
    const float* oph = (const float*)d_in[3];

    build_all<<<dim3(NBLK), dim3(256), 0, stream>>>(mzi, oph);
    if (out_size == BDIM * NDIM) {
        cmatmul0<<<dim3(BDIM / 64), dim3(256), 0, stream>>>(xr, xi, (float*)d_out);
    } else {
        cmatmul1<<<dim3(BDIM / 64), dim3(256), 0, stream>>>(xr, xi, (ushort2*)d_out);
    }
}

// Round 15
// 127.663 us; speedup vs baseline: 1.3237x; 1.3237x over previous
//
#include <hip/hip_runtime.h>
#include <hip/hip_bf16.h>

#define NDIM 128
#define N2   (NDIM * NDIM)
#define BDIM 131072
#define NMZI 8128                       // 128*127/2
#define NCHUNK 16                       // chunks of 8 sweeps (last: 7)
#define NBLK 128                        // 64 build blocks + all join compose
#define NJG 8                           // j-groups per block (scan groups)
#define NCOL 32                         // columns per block
#define NLOC 16                         // max local scan length = ceil(127/8)
static constexpr float CC = 0.70710678118654752440f;  // sqrt(0.5)

typedef __attribute__((ext_vector_type(8))) short bf16x8;
typedef __attribute__((ext_vector_type(4))) float f32x4;

// Static device scratch (d_ws size unknown -> don't touch it)
__device__ __align__(16) float2         g_V[NCHUNK * N2];   // chunk partial unitaries (2 MB)
__device__ __align__(16) float2         g_W[4 * N2];        // group products W_g
// Packed K=256 table for real-output GEMM: kg2<16 -> Ur[k=kg2*8+e][n]; kg2>=16 -> -Ui
__device__ __align__(16) unsigned short g_TB[32 * NDIM * 8];        // 64 KB
// Separate tables for the (unlikely) complex-interleaved output mode
__device__ __align__(16) unsigned short g_Ur[16 * NDIM * 8];
__device__ __align__(16) unsigned short g_Ui[16 * NDIM * 8];
// grid-barrier counters (monotonic within build_all; reset ATOMICALLY by the
// following cmatmul launch — never mid-kernel, so no spin/reset race)
__device__ unsigned g_ctr[3];

__device__ inline unsigned short f2bf(float f) {
    union { __hip_bfloat16 h; unsigned short u; } cv;
    cv.h = __float2bfloat16(f);
    return cv.u;
}

// ---- device-scope grid barrier: RELAXED spin (no per-poll cache invalidate) ----
__device__ __forceinline__ void gbar(int idx) {
    __syncthreads();
    asm volatile("" ::: "memory");
    if (threadIdx.x == 0) {
        __threadfence();   // release: my global writes reach device scope
        __hip_atomic_fetch_add(&g_ctr[idx], 1u, __ATOMIC_RELEASE, __HIP_MEMORY_SCOPE_AGENT);
        while (__hip_atomic_load(&g_ctr[idx], __ATOMIC_RELAXED, __HIP_MEMORY_SCOPE_AGENT)
               < (unsigned)NBLK)
            __builtin_amdgcn_s_sleep(2);
        __threadfence();   // acquire ONCE after exit: invalidate stale lines
    }
    __syncthreads();
    asm volatile("" ::: "memory");
}

#define CFMA(acc, av, b)                                                    \
    acc.x = fmaf(av.x, b.x, fmaf(-av.y, b.y, acc.x));                       \
    acc.y = fmaf(av.x, b.y, fmaf( av.y, b.x, acc.y));

// ---------------- K1: build 16 chunks + 2-level row-chained compose, ONE kernel ----
// 128 blocks x 256 threads.
// Phase A (blocks 0..63 = 4 col-slabs x 16 chunks): sweep-aligned affine-scan
//   (R10-verified body), 8 sweeps per chunk -> g_V.
// gbar -> Phase B: block b computes 4 rows of W_g = V_{4g+3}..V_{4g} via 3
//   sequential vec×mat products (8-deep B-prefetch, intermediates in LDS).
// gbar -> Phase C: block b computes row b of U = W3*W2*W1*W0 (3 products),
//   applies diag, packs bf16 tables.
__global__ __launch_bounds__(256) void build_all(const float* __restrict__ mzi,
                                                 const float* __restrict__ oph) {
    __shared__ __align__(16) char SM[40960];
    const int tid = threadIdx.x;
    const int b   = blockIdx.x;

    if (b < 64) {
        // ---- phase A: build chunk partial unitary ----
        float2 (*Usm)[NCOL] = reinterpret_cast<float2(*)[NCOL]>(SM);          // 32 KB
        float4 (*ph)[NDIM]  = reinterpret_cast<float4(*)[NDIM]>(SM + 32768);  // 4 KB
        float4 (*cmp)[NCOL] = reinterpret_cast<float4(*)[NCOL]>(SM + 36864);  // 4 KB
        const int c     = tid & 31;
        const int g     = tid >> 5;
        const int col0  = (b & 3) * NCOL;
        const int chunk = b >> 2;                 // 0..15
        const int i0    = chunk * 8;
        const int iEnd  = min(i0 + 8, NDIM - 1);  // sweeps [i0, iEnd)
        const int nsw   = iEnd - i0;

        for (int k = g; k < NDIM; k += NJG)
            Usm[k][c] = make_float2((k == col0 + c) ? 1.f : 0.f, 0.f);

        const float2* mzp = (const float2*)mzi;   // (theta, phi) pairs
        int base = 127 * i0 - (i0 * (i0 - 1)) / 2;
        {
            const int L0 = NDIM - 1 - i0;
            if (tid < L0) {
                const float2 mz = mzp[base + tid];
                float sp, cp, st, ct;
                sincosf(mz.y, &sp, &cp);
                sincosf(mz.x, &st, &ct);
                ph[0][tid] = make_float4(cp, sp, CC * ct, CC * st);
            }
        }
        __syncthreads();

        #pragma unroll 1
        for (int sw = 0; sw < nsw; ++sw) {
            const int i = i0 + sw;
            const int L = NDIM - 1 - i;           // sweep length (>=1)
            const int cur = sw & 1;

            float2 mznext;
            const bool have = (sw < nsw - 1) && (tid < L - 1);
            if (have) mznext = mzp[base + L + tid];

            const float2 r0 = Usm[i][c];          // read BEFORE barrier
            const int nloc  = (L + NJG - 1) >> 3;
            const int myBeg = g * nloc;
            const int myN   = max(0, min(nloc, L - myBeg));

            float2 treg[NLOC];
            float2 qth[NLOC];
            float  A = 1.f;
            float2 Bc = make_float2(0.f, 0.f);
            #pragma unroll
            for (int kk = 0; kk < NLOC; ++kk) {
                if (kk < myN) {
                    const int off = myBeg + kk;
                    const float4 q  = ph[cur][off];
                    const float2 rj = Usm[i + 1 + off][c];
                    const float tr = fmaf(q.x, rj.x, -q.y * rj.y);
                    const float ti = fmaf(q.x, rj.y,  q.y * rj.x);
                    treg[kk] = make_float2(tr, ti);
                    qth[kk]  = make_float2(q.z, q.w);
                    Bc.x = CC * (Bc.x + tr);
                    Bc.y = CC * (Bc.y + ti);
                    A *= CC;
                }
            }
            cmp[g][c] = make_float4(A, Bc.x, Bc.y, 0.f);
            __syncthreads();

            float2 r = r0;
            for (int h2 = 0; h2 < g; ++h2) {
                const float4 cm = cmp[h2][c];
                r.x = fmaf(cm.x, r.x, cm.y);
                r.y = fmaf(cm.x, r.y, cm.z);
            }

            #pragma unroll
            for (int kk = 0; kk < NLOC; ++kk) {
                if (kk < myN) {
                    const float2 t = treg[kk];
                    const float2 q = qth[kk];
                    const float dr = r.x - t.x, di = r.y - t.y;
                    const float njx = fmaf(q.x, dr, -q.y * di);
                    const float njy = fmaf(q.x, di,  q.y * dr);
                    Usm[i + 1 + myBeg + kk][c] = make_float2(njx, njy);
                    r.x = CC * (r.x + t.x);
                    r.y = CC * (r.y + t.y);
                }
            }
            if (myN > 0 && (myBeg + myN == L))
                Usm[i][c] = r;

            if (have) {
                float sp, cp, st, ct;
                sincosf(mznext.y, &sp, &cp);
                sincosf(mznext.x, &st, &ct);
                ph[cur ^ 1][tid] = make_float4(cp, sp, CC * ct, CC * st);
            }
            __syncthreads();
            base += L;
        }

        float2* Vp = g_V + chunk * N2;
        for (int k = g; k < NDIM; k += NJG)
            Vp[k * NDIM + col0 + c] = Usm[k][c];
    }

    gbar(0);   // all 16 g_V chunks visible device-wide

    // ---- phase B: W_g = V_{4g+3}*V_{4g+2}*V_{4g+1}*V_{4g}, 4 rows per block ----
    {
        const int gq  = b >> 5;               // group 0..3
        const int n0  = (b & 31) * 4;         // output rows
        const int m   = tid & 127;
        const bool act = tid < 128;
        float2* As = (float2*)SM;             // 4 rows x 128 = 4 KB

        __syncthreads();
        if (act) {
            const float2* A = g_V + (4 * gq + 3) * N2;
            #pragma unroll
            for (int r = 0; r < 4; ++r) As[r * NDIM + m] = A[(n0 + r) * NDIM + m];
        }
        __syncthreads();

        #pragma unroll 1
        for (int step = 2; step >= 0; --step) {
            float2 acc[4];
            #pragma unroll
            for (int r = 0; r < 4; ++r) acc[r] = make_float2(0.f, 0.f);
            if (act) {
                const float2* B = g_V + (4 * gq + step) * N2;  // overrun -> next V: safe
                float2 bb[8];
                #pragma unroll
                for (int u = 0; u < 8; ++u) bb[u] = B[u * NDIM + m];
                #pragma unroll 1
                for (int k0 = 0; k0 < NDIM; k0 += 8) {
                    #pragma unroll
                    for (int u = 0; u < 8; ++u) {
                        const float2 bv = bb[u];
                        bb[u] = B[(k0 + 8 + u) * NDIM + m];
                        const int k = k0 + u;
                        #pragma unroll
                        for (int r = 0; r < 4; ++r) {
                            const float2 av = As[r * NDIM + k];   // broadcast
                            CFMA(acc[r], av, bv)
                        }
                    }
                }
            }
            __syncthreads();                  // all As reads done
            if (act) {
                if (step > 0) {
                    #pragma unroll
                    for (int r = 0; r < 4; ++r) As[r * NDIM + m] = acc[r];
                } else {
                    #pragma unroll
                    for (int r = 0; r < 4; ++r)
                        g_W[gq * N2 + (n0 + r) * NDIM + m] = acc[r];
                }
            }
            __syncthreads();
        }
    }

    gbar(1);   // all g_W visible

    // ---- phase C: row b of U = W3*W2*W1*W0; diag; pack ----
    {
        const int n   = b;                    // 128 blocks = 128 rows
        const int m   = tid & 127;
        const bool act = tid < 128;
        float2* As = (float2*)SM;             // 1 row x 128

        __syncthreads();
        if (act) As[m] = g_W[3 * N2 + n * NDIM + m];
        __syncthreads();

        #pragma unroll 1
        for (int step = 2; step >= 0; --step) {
            float2 acc = make_float2(0.f, 0.f);
            if (act) {
                const float2* B = g_W + step * N2;   // overrun -> next W: safe
                float2 bb[8];
                #pragma unroll
                for (int u = 0; u < 8; ++u) bb[u] = B[u * NDIM + m];
                #pragma unroll 1
                for (int k0 = 0; k0 < NDIM; k0 += 8) {
                    #pragma unroll
                    for (int u = 0; u < 8; ++u) {
                        const float2 bv = bb[u];
                        bb[u] = B[(k0 + 8 + u) * NDIM + m];
                        const float2 av = As[k0 + u];            // broadcast
                        CFMA(acc, av, bv)
                    }
                }
            }
            __syncthreads();
            if (act) {
                if (step > 0) {
                    As[m] = acc;
                } else {
                    float ds, dc;
                    sincosf(oph[n], &ds, &dc);
                    const float vr = fmaf(acc.x, dc, -acc.y * ds);
                    const float vi = fmaf(acc.x, ds,  acc.y * dc);
                    const int kg = m >> 3, e = m & 7;
                    g_TB[(kg * NDIM + n) * 8 + e]        = f2bf(vr);
                    g_TB[((16 + kg) * NDIM + n) * 8 + e] = f2bf(-vi);
                    g_Ur[(kg * NDIM + n) * 8 + e] = f2bf(vr);
                    g_Ui[(kg * NDIM + n) * 8 + e] = f2bf(vi);
                }
            }
            __syncthreads();
        }
    }
}

// ---------------- K2a: real-output GEMM (R10-verified, 49.3 us) ----------------
__global__ __launch_bounds__(256) void cmatmul0(const float* __restrict__ xr,
                                                const float* __restrict__ xi,
                                                float* __restrict__ out) {
    if (blockIdx.x == 0 && threadIdx.x == 0) {    // reset barrier counters at
        #pragma unroll                            // device scope (visible to
        for (int i = 0; i < 3; ++i)               // next replay's atomics)
            __hip_atomic_store(&g_ctr[i], 0u, __ATOMIC_RELAXED, __HIP_MEMORY_SCOPE_AGENT);
    }
    __shared__ __align__(16) char smX[4][8192];   // per-wave tile buffer
    const int tid  = threadIdx.x;
    const int lane = tid & 63;
    const int w    = tid >> 6;
    const int r15  = lane & 15;
    const int kg4  = lane >> 4;
    const int l31  = lane & 31;
    const int lh   = lane >> 5;
    const int R    = blockIdx.x * 64 + w * 16;    // wave's tile base row

    const f32x4* sre = (const f32x4*)(xr + (size_t)R * NDIM);
    const f32x4* sim = (const f32x4*)(xi + (size_t)R * NDIM);
    f32x4 G[16];
    #pragma unroll
    for (int p = 0; p < 8; ++p) G[p]     = __builtin_nontemporal_load(sre + p * 64 + lane);
    #pragma unroll
    for (int p = 0; p < 8; ++p) G[8 + p] = __builtin_nontemporal_load(sim + p * 64 + lane);

    char* buf = &smX[w][0];
    #pragma unroll
    for (int p = 0; p < 8; ++p) {
        const int row = 2 * p + lh;
        const int swz = (row & 7) << 4;
        uint2 v;
        v.x = ((unsigned)f2bf(G[p][1]) << 16) | f2bf(G[p][0]);
        v.y = ((unsigned)f2bf(G[p][3]) << 16) | f2bf(G[p][2]);
        *(uint2*)(buf + row * 512 + ((l31 * 8) ^ swz)) = v;
        v.x = ((unsigned)f2bf(G[8 + p][1]) << 16) | f2bf(G[8 + p][0]);
        v.y = ((unsigned)f2bf(G[8 + p][3]) << 16) | f2bf(G[8 + p][2]);
        *(uint2*)(buf + row * 512 + 256 + ((l31 * 8) ^ swz)) = v;
    }

    bf16x8 fx[8];
    const int rswz = (r15 & 7) << 4;
    #pragma unroll
    for (int kc = 0; kc < 8; ++kc) {
        const int off = (((kc & 3) * 64 + kg4 * 16) ^ rswz) + ((kc >= 4) ? 256 : 0);
        fx[kc] = *(const bf16x8*)(buf + r15 * 512 + off);
    }

    const bf16x8* gT = (const bf16x8*)g_TB;
    #pragma unroll
    for (int nt = 0; nt < 8; ++nt) {
        f32x4 a0 = {0.f, 0.f, 0.f, 0.f};
        f32x4 a1 = {0.f, 0.f, 0.f, 0.f};
        #pragma unroll
        for (int kc = 0; kc < 4; ++kc)
            a0 = __builtin_amdgcn_mfma_f32_16x16x32_bf16(
                gT[(kc * 4 + kg4) * NDIM + nt * 16 + r15], fx[kc], a0, 0, 0, 0);
        #pragma unroll
        for (int kc = 4; kc < 8; ++kc)
            a1 = __builtin_amdgcn_mfma_f32_16x16x32_bf16(
                gT[(kc * 4 + kg4) * NDIM + nt * 16 + r15], fx[kc], a1, 0, 0, 0);
        const f32x4 s = a0 + a1;
        *(f32x4*)(buf + r15 * 512 + ((nt * 64 + kg4 * 16) ^ rswz)) = s;
    }

    char* outp = (char*)(out + (size_t)R * NDIM);
    #pragma unroll
    for (int p = 0; p < 8; ++p) {
        const int bofs = p * 1024 + lane * 16;
        const int row  = bofs >> 9;
        const int colb = bofs & 511;
        const f32x4 v = *(const f32x4*)(buf + row * 512 + (colb ^ ((row & 7) << 4)));
        __builtin_nontemporal_store(v, (f32x4*)(outp + bofs));
    }
}

// ---------------- K2b: complex-output fallback (bf16 re,im pairs) ----------------
__global__ __launch_bounds__(256) void cmatmul1(const float* __restrict__ xr,
                                                const float* __restrict__ xi,
                                                ushort2* __restrict__ outp) {
    if (blockIdx.x == 0 && threadIdx.x == 0) {
        #pragma unroll
        for (int i = 0; i < 3; ++i)
            __hip_atomic_store(&g_ctr[i], 0u, __ATOMIC_RELAXED, __HIP_MEMORY_SCOPE_AGENT);
    }
    const int lane  = threadIdx.x & 63;
    const int w     = threadIdx.x >> 6;
    const int btile = blockIdx.x * 64 + w * 16;
    const int r15   = lane & 15;
    const int kg4   = lane >> 4;
    const int bload = btile + r15;

    const bf16x8* Ur = (const bf16x8*)g_Ur;
    const bf16x8* Ui = (const bf16x8*)g_Ui;
    const float* xrp = xr + (size_t)bload * NDIM;
    const float* xip = xi + (size_t)bload * NDIM;

    bf16x8 ar[4], ai[4], ain[4];
    #pragma unroll
    for (int kc = 0; kc < 4; ++kc) {
        const int k0 = kc * 32 + kg4 * 8;
        float4 rlo = *(const float4*)(xrp + k0);
        float4 rhi = *(const float4*)(xrp + k0 + 4);
        float4 ilo = *(const float4*)(xip + k0);
        float4 ihi = *(const float4*)(xip + k0 + 4);
        bf16x8 vr, vi, vn;
        vr[0] = (short)f2bf(rlo.x); vr[1] = (short)f2bf(rlo.y);
        vr[2] = (short)f2bf(rlo.z); vr[3] = (short)f2bf(rlo.w);
        vr[4] = (short)f2bf(rhi.x); vr[5] = (short)f2bf(rhi.y);
        vr[6] = (short)f2bf(rhi.z); vr[7] = (short)f2bf(rhi.w);
        vi[0] = (short)f2bf(ilo.x); vi[1] = (short)f2bf(ilo.y);
        vi[2] = (short)f2bf(ilo.z); vi[3] = (short)f2bf(ilo.w);
        vi[4] = (short)f2bf(ihi.x); vi[5] = (short)f2bf(ihi.y);
        vi[6] = (short)f2bf(ihi.z); vi[7] = (short)f2bf(ihi.w);
        #pragma unroll
        for (int e = 0; e < 8; ++e) vn[e] = (short)(vi[e] ^ 0x8000);
        ar[kc] = vr; ai[kc] = vi; ain[kc] = vn;
    }

    #pragma unroll
    for (int nt = 0; nt < 8; ++nt) {
        f32x4 accR = {0.f, 0.f, 0.f, 0.f};
        f32x4 accI = {0.f, 0.f, 0.f, 0.f};
        #pragma unroll
        for (int kc = 0; kc < 4; ++kc) {
            const int kg = kc * 4 + kg4;
            bf16x8 br = Ur[kg * NDIM + nt * 16 + r15];
            bf16x8 bi = Ui[kg * NDIM + nt * 16 + r15];
            accR = __builtin_amdgcn_mfma_f32_16x16x32_bf16(ar[kc],  br, accR, 0, 0, 0);
            accR = __builtin_amdgcn_mfma_f32_16x16x32_bf16(ain[kc], bi, accR, 0, 0, 0);
            accI = __builtin_amdgcn_mfma_f32_16x16x32_bf16(ar[kc],  bi, accI, 0, 0, 0);
            accI = __builtin_amdgcn_mfma_f32_16x16x32_bf16(ai[kc],  br, accI, 0, 0, 0);
        }
        const int n    = nt * 16 + r15;
        const int brow = btile + kg4 * 4;
        #pragma unroll
        for (int r = 0; r < 4; ++r)
            outp[(size_t)(brow + r) * NDIM + n] = make_ushort2(f2bf(accR[r]), f2bf(accI[r]));
    }
}

extern "C" void kernel_launch(void* const* d_in, const int* in_sizes, int n_in,
                              void* d_out, int out_size, void* d_ws, size_t ws_size,
                              hipStream_t stream) {
    const float* xr  = (const float*)d_in[0];
    const float* xi  = (const float*)d_in[1];
    const float* mzi = (const float*)d_in[2];
    const float* oph = (const float*)d_in[3];

    build_all<<<dim3(NBLK), dim3(256), 0, stream>>>(mzi, oph);
    if (out_size == BDIM * NDIM) {
        cmatmul0<<<dim3(BDIM / 64), dim3(256), 0, stream>>>(xr, xi, (float*)d_out);
    } else {
        cmatmul1<<<dim3(BDIM / 64), dim3(256), 0, stream>>>(xr, xi, (ushort2*)d_out);
    }
}

// Round 16
// 110.398 us; speedup vs baseline: 1.5308x; 1.1564x over previous
//
#include <hip/hip_runtime.h>
#include <hip/hip_bf16.h>

#define NDIM 128
#define N2   (NDIM * NDIM)
#define BDIM 131072
#define NMZI 8128                       // 128*127/2
#define NCHUNK 16                       // chunks of 8 sweeps (last: 7)
#define NJG 8                           // j-groups per block (scan groups)
#define NCOL 32                         // columns per block
#define NLOC 16                         // max local scan length = ceil(127/8)
static constexpr float CC = 0.70710678118654752440f;  // sqrt(0.5)

typedef __attribute__((ext_vector_type(8))) short bf16x8;
typedef __attribute__((ext_vector_type(4))) float f32x4;

// Static device scratch (d_ws size unknown -> don't touch it)
// Declaration order matters: B-prefetch overruns (<=8 rows) from the last
// matrix of g_V land in g_W, and from W2 land in W3 — all mapped memory.
__device__ __align__(16) float2         g_V[NCHUNK * N2];   // chunk partial unitaries (2 MB)
__device__ __align__(16) float2         g_W[4 * N2];        // quad-group products W_g
// Packed K=256 table for real-output GEMM: kg2<16 -> Ur[k=kg2*8+e][n]; kg2>=16 -> -Ui
__device__ __align__(16) unsigned short g_TB[32 * NDIM * 8];        // 64 KB
// Separate tables for the (unlikely) complex-interleaved output mode
__device__ __align__(16) unsigned short g_Ur[16 * NDIM * 8];
__device__ __align__(16) unsigned short g_Ui[16 * NDIM * 8];

__device__ inline unsigned short f2bf(float f) {
    union { __hip_bfloat16 h; unsigned short u; } cv;
    cv.h = __float2bfloat16(f);
    return cv.u;
}

#define CFMA(acc, av, b)                                                    \
    acc.x = fmaf(av.x, b.x, fmaf(-av.y, b.y, acc.x));                       \
    acc.y = fmaf(av.x, b.y, fmaf( av.y, b.x, acc.y));

// ---------------- K1: build chunk partial unitaries (sweep-aligned affine-scan) ----
// grid (4 col-slabs, 16 chunks) x 256 threads; 8 sweeps per chunk.
// R15-verified body.
__global__ __launch_bounds__(256) void build_scan(const float* __restrict__ mzi) {
    __shared__ float2 Usm[NDIM][NCOL];        // 32 KB
    __shared__ float4 ph[2][NDIM];            // 4 KB: cur/next sweep phases
    __shared__ float4 cmp[NJG][NCOL];         // 4 KB
    const int tid   = threadIdx.x;
    const int c     = tid & 31;
    const int g     = tid >> 5;
    const int col0  = blockIdx.x * NCOL;
    const int chunk = blockIdx.y;             // 0..15
    const int i0    = chunk * 8;
    const int iEnd  = min(i0 + 8, NDIM - 1);  // sweeps [i0, iEnd)
    const int nsw   = iEnd - i0;

    for (int k = g; k < NDIM; k += NJG)
        Usm[k][c] = make_float2((k == col0 + c) ? 1.f : 0.f, 0.f);

    const float2* mzp = (const float2*)mzi;   // (theta, phi) pairs
    int base = 127 * i0 - (i0 * (i0 - 1)) / 2;
    {
        const int L0 = NDIM - 1 - i0;
        if (tid < L0) {
            const float2 mz = mzp[base + tid];
            float sp, cp, st, ct;
            sincosf(mz.y, &sp, &cp);
            sincosf(mz.x, &st, &ct);
            ph[0][tid] = make_float4(cp, sp, CC * ct, CC * st);
        }
    }
    __syncthreads();

    #pragma unroll 1
    for (int sw = 0; sw < nsw; ++sw) {
        const int i = i0 + sw;
        const int L = NDIM - 1 - i;           // sweep length (>=1)
        const int cur = sw & 1;

        float2 mznext;
        const bool have = (sw < nsw - 1) && (tid < L - 1);
        if (have) mznext = mzp[base + L + tid];

        const float2 r0 = Usm[i][c];          // read BEFORE barrier
        const int nloc  = (L + NJG - 1) >> 3;
        const int myBeg = g * nloc;
        const int myN   = max(0, min(nloc, L - myBeg));

        float2 treg[NLOC];
        float2 qth[NLOC];
        float  A = 1.f;
        float2 Bc = make_float2(0.f, 0.f);
        #pragma unroll
        for (int kk = 0; kk < NLOC; ++kk) {
            if (kk < myN) {
                const int off = myBeg + kk;
                const float4 q  = ph[cur][off];
                const float2 rj = Usm[i + 1 + off][c];
                const float tr = fmaf(q.x, rj.x, -q.y * rj.y);
                const float ti = fmaf(q.x, rj.y,  q.y * rj.x);
                treg[kk] = make_float2(tr, ti);
                qth[kk]  = make_float2(q.z, q.w);
                Bc.x = CC * (Bc.x + tr);
                Bc.y = CC * (Bc.y + ti);
                A *= CC;
            }
        }
        cmp[g][c] = make_float4(A, Bc.x, Bc.y, 0.f);
        __syncthreads();

        float2 r = r0;
        for (int h2 = 0; h2 < g; ++h2) {
            const float4 cm = cmp[h2][c];
            r.x = fmaf(cm.x, r.x, cm.y);
            r.y = fmaf(cm.x, r.y, cm.z);
        }

        #pragma unroll
        for (int kk = 0; kk < NLOC; ++kk) {
            if (kk < myN) {
                const float2 t = treg[kk];
                const float2 q = qth[kk];
                const float dr = r.x - t.x, di = r.y - t.y;
                const float njx = fmaf(q.x, dr, -q.y * di);
                const float njy = fmaf(q.x, di,  q.y * dr);
                Usm[i + 1 + myBeg + kk][c] = make_float2(njx, njy);
                r.x = CC * (r.x + t.x);
                r.y = CC * (r.y + t.y);
            }
        }
        if (myN > 0 && (myBeg + myN == L))
            Usm[i][c] = r;

        if (have) {
            float sp, cp, st, ct;
            sincosf(mznext.y, &sp, &cp);
            sincosf(mznext.x, &st, &ct);
            ph[cur ^ 1][tid] = make_float4(cp, sp, CC * ct, CC * st);
        }
        __syncthreads();
        base += L;
    }

    float2* Vp = g_V + chunk * N2;
    for (int k = g; k < NDIM; k += NJG)
        Vp[k * NDIM + col0 + c] = Usm[k][c];
}

// ---------------- K2: W_g = V_{4g+3}*V_{4g+2}*V_{4g+1}*V_{4g} ----------------
// grid (32 row-groups, 4 groups) x 256 threads. Block computes 4 rows of W_g
// via 3 chained vec×mat products. k-SPLIT: each half-block (128 thr) sums its
// 64 k's with 8-deep register B-prefetch (halves the latency chain); halves
// combined via LDS between products.
__global__ __launch_bounds__(256) void compose_quad() {
    __shared__ float2 As[4 * NDIM];           // current accumulated rows (4 KB)
    __shared__ float2 part[2][4][NDIM];       // per-half partials (8 KB)
    const int tid = threadIdx.x;
    const int h   = tid >> 7;
    const int m   = tid & 127;
    const int gq  = blockIdx.y;
    const int n0  = blockIdx.x * 4;

    if (h == 0) {
        const float2* A = g_V + (4 * gq + 3) * N2;
        #pragma unroll
        for (int r = 0; r < 4; ++r) As[r * NDIM + m] = A[(n0 + r) * NDIM + m];
    }
    __syncthreads();

    #pragma unroll 1
    for (int step = 2; step >= 0; --step) {
        const float2* B = g_V + (4 * gq + step) * N2;
        const int kbase = h * 64;
        float2 a0 = {0.f, 0.f}, a1 = {0.f, 0.f}, a2 = {0.f, 0.f}, a3 = {0.f, 0.f};
        float2 bb[8];
        #pragma unroll
        for (int u = 0; u < 8; ++u) bb[u] = B[(kbase + u) * NDIM + m];
        #pragma unroll 1
        for (int k0 = 0; k0 < 64; k0 += 8) {
            #pragma unroll
            for (int u = 0; u < 8; ++u) {
                const float2 bv = bb[u];
                bb[u] = B[(kbase + k0 + 8 + u) * NDIM + m];   // overrun: next matrix, safe
                const int k = kbase + k0 + u;
                float2 av;
                av = As[0 * NDIM + k]; CFMA(a0, av, bv)
                av = As[1 * NDIM + k]; CFMA(a1, av, bv)
                av = As[2 * NDIM + k]; CFMA(a2, av, bv)
                av = As[3 * NDIM + k]; CFMA(a3, av, bv)
            }
        }
        part[h][0][m] = a0; part[h][1][m] = a1;
        part[h][2][m] = a2; part[h][3][m] = a3;
        __syncthreads();                      // As reads done, parts visible
        if (h == 0) {
            #pragma unroll
            for (int r = 0; r < 4; ++r) {
                const float2 p0 = part[0][r][m], p1 = part[1][r][m];
                const float2 s = make_float2(p0.x + p1.x, p0.y + p1.y);
                if (step > 0) As[r * NDIM + m] = s;
                else          g_W[gq * N2 + (n0 + r) * NDIM + m] = s;
            }
        }
        __syncthreads();
    }
}

// ---------------- K3: U = W3*W2*W1*W0, diag, pack bf16 tables ----------------
// grid (32) x 256 threads; block computes 4 rows (same chained structure).
__global__ __launch_bounds__(256) void compose_final4(const float* __restrict__ oph) {
    __shared__ float2 As[4 * NDIM];
    __shared__ float2 part[2][4][NDIM];
    const int tid = threadIdx.x;
    const int h   = tid >> 7;
    const int m   = tid & 127;
    const int n0  = blockIdx.x * 4;

    if (h == 0) {
        const float2* A = g_W + 3 * N2;
        #pragma unroll
        for (int r = 0; r < 4; ++r) As[r * NDIM + m] = A[(n0 + r) * NDIM + m];
    }
    __syncthreads();

    #pragma unroll 1
    for (int step = 2; step >= 0; --step) {
        const float2* B = g_W + step * N2;
        const int kbase = h * 64;
        float2 a0 = {0.f, 0.f}, a1 = {0.f, 0.f}, a2 = {0.f, 0.f}, a3 = {0.f, 0.f};
        float2 bb[8];
        #pragma unroll
        for (int u = 0; u < 8; ++u) bb[u] = B[(kbase + u) * NDIM + m];
        #pragma unroll 1
        for (int k0 = 0; k0 < 64; k0 += 8) {
            #pragma unroll
            for (int u = 0; u < 8; ++u) {
                const float2 bv = bb[u];
                bb[u] = B[(kbase + k0 + 8 + u) * NDIM + m];   // overrun: next W, safe
                const int k = kbase + k0 + u;
                float2 av;
                av = As[0 * NDIM + k]; CFMA(a0, av, bv)
                av = As[1 * NDIM + k]; CFMA(a1, av, bv)
                av = As[2 * NDIM + k]; CFMA(a2, av, bv)
                av = As[3 * NDIM + k]; CFMA(a3, av, bv)
            }
        }
        part[h][0][m] = a0; part[h][1][m] = a1;
        part[h][2][m] = a2; part[h][3][m] = a3;
        __syncthreads();
        if (h == 0) {
            if (step > 0) {
                #pragma unroll
                for (int r = 0; r < 4; ++r) {
                    const float2 p0 = part[0][r][m], p1 = part[1][r][m];
                    As[r * NDIM + m] = make_float2(p0.x + p1.x, p0.y + p1.y);
                }
            } else {
                const int kg = m >> 3, e = m & 7;
                #pragma unroll
                for (int r = 0; r < 4; ++r) {
                    const float2 p0 = part[0][r][m], p1 = part[1][r][m];
                    const float2 u = make_float2(p0.x + p1.x, p0.y + p1.y);
                    const int n = n0 + r;
                    float ds, dc;
                    sincosf(oph[n], &ds, &dc);
                    const float vr = fmaf(u.x, dc, -u.y * ds);
                    const float vi = fmaf(u.x, ds,  u.y * dc);
                    g_TB[(kg * NDIM + n) * 8 + e]        = f2bf(vr);
                    g_TB[((16 + kg) * NDIM + n) * 8 + e] = f2bf(-vi);
                    g_Ur[(kg * NDIM + n) * 8 + e] = f2bf(vr);
                    g_Ui[(kg * NDIM + n) * 8 + e] = f2bf(vi);
                }
            }
        }
        __syncthreads();
    }
}

// ---------------- K4a: real-output GEMM (R10-verified, 49.3 us) ----------------
__global__ __launch_bounds__(256) void cmatmul0(const float* __restrict__ xr,
                                                const float* __restrict__ xi,
                                                float* __restrict__ out) {
    __shared__ __align__(16) char smX[4][8192];   // per-wave tile buffer
    const int tid  = threadIdx.x;
    const int lane = tid & 63;
    const int w    = tid >> 6;
    const int r15  = lane & 15;
    const int kg4  = lane >> 4;
    const int l31  = lane & 31;
    const int lh   = lane >> 5;
    const int R    = blockIdx.x * 64 + w * 16;    // wave's tile base row

    const f32x4* sre = (const f32x4*)(xr + (size_t)R * NDIM);
    const f32x4* sim = (const f32x4*)(xi + (size_t)R * NDIM);
    f32x4 G[16];
    #pragma unroll
    for (int p = 0; p < 8; ++p) G[p]     = __builtin_nontemporal_load(sre + p * 64 + lane);
    #pragma unroll
    for (int p = 0; p < 8; ++p) G[8 + p] = __builtin_nontemporal_load(sim + p * 64 + lane);

    char* buf = &smX[w][0];
    #pragma unroll
    for (int p = 0; p < 8; ++p) {
        const int row = 2 * p + lh;
        const int swz = (row & 7) << 4;
        uint2 v;
        v.x = ((unsigned)f2bf(G[p][1]) << 16) | f2bf(G[p][0]);
        v.y = ((unsigned)f2bf(G[p][3]) << 16) | f2bf(G[p][2]);
        *(uint2*)(buf + row * 512 + ((l31 * 8) ^ swz)) = v;
        v.x = ((unsigned)f2bf(G[8 + p][1]) << 16) | f2bf(G[8 + p][0]);
        v.y = ((unsigned)f2bf(G[8 + p][3]) << 16) | f2bf(G[8 + p][2]);
        *(uint2*)(buf + row * 512 + 256 + ((l31 * 8) ^ swz)) = v;
    }

    bf16x8 fx[8];
    const int rswz = (r15 & 7) << 4;
    #pragma unroll
    for (int kc = 0; kc < 8; ++kc) {
        const int off = (((kc & 3) * 64 + kg4 * 16) ^ rswz) + ((kc >= 4) ? 256 : 0);
        fx[kc] = *(const bf16x8*)(buf + r15 * 512 + off);
    }

    const bf16x8* gT = (const bf16x8*)g_TB;
    #pragma unroll
    for (int nt = 0; nt < 8; ++nt) {
        f32x4 a0 = {0.f, 0.f, 0.f, 0.f};
        f32x4 a1 = {0.f, 0.f, 0.f, 0.f};
        #pragma unroll
        for (int kc = 0; kc < 4; ++kc)
            a0 = __builtin_amdgcn_mfma_f32_16x16x32_bf16(
                gT[(kc * 4 + kg4) * NDIM + nt * 16 + r15], fx[kc], a0, 0, 0, 0);
        #pragma unroll
        for (int kc = 4; kc < 8; ++kc)
            a1 = __builtin_amdgcn_mfma_f32_16x16x32_bf16(
                gT[(kc * 4 + kg4) * NDIM + nt * 16 + r15], fx[kc], a1, 0, 0, 0);
        const f32x4 s = a0 + a1;
        *(f32x4*)(buf + r15 * 512 + ((nt * 64 + kg4 * 16) ^ rswz)) = s;
    }

    char* outp = (char*)(out + (size_t)R * NDIM);
    #pragma unroll
    for (int p = 0; p < 8; ++p) {
        const int bofs = p * 1024 + lane * 16;
        const int row  = bofs >> 9;
        const int colb = bofs & 511;
        const f32x4 v = *(const f32x4*)(buf + row * 512 + (colb ^ ((row & 7) << 4)));
        __builtin_nontemporal_store(v, (f32x4*)(outp + bofs));
    }
}

// ---------------- K4b: complex-output fallback (bf16 re,im pairs) ----------------
__global__ __launch_bounds__(256) void cmatmul1(const float* __restrict__ xr,
                                                const float* __restrict__ xi,
                                                ushort2* __restrict__ outp) {
    const int lane  = threadIdx.x & 63;
    const int w     = threadIdx.x >> 6;
    const int btile = blockIdx.x * 64 + w * 16;
    const int r15   = lane & 15;
    const int kg4   = lane >> 4;
    const int bload = btile + r15;

    const bf16x8* Ur = (const bf16x8*)g_Ur;
    const bf16x8* Ui = (const bf16x8*)g_Ui;
    const float* xrp = xr + (size_t)bload * NDIM;
    const float* xip = xi + (size_t)bload * NDIM;

    bf16x8 ar[4], ai[4], ain[4];
    #pragma unroll
    for (int kc = 0; kc < 4; ++kc) {
        const int k0 = kc * 32 + kg4 * 8;
        float4 rlo = *(const float4*)(xrp + k0);
        float4 rhi = *(const float4*)(xrp + k0 + 4);
        float4 ilo = *(const float4*)(xip + k0);
        float4 ihi = *(const float4*)(xip + k0 + 4);
        bf16x8 vr, vi, vn;
        vr[0] = (short)f2bf(rlo.x); vr[1] = (short)f2bf(rlo.y);
        vr[2] = (short)f2bf(rlo.z); vr[3] = (short)f2bf(rlo.w);
        vr[4] = (short)f2bf(rhi.x); vr[5] = (short)f2bf(rhi.y);
        vr[6] = (short)f2bf(rhi.z); vr[7] = (short)f2bf(rhi.w);
        vi[0] = (short)f2bf(ilo.x); vi[1] = (short)f2bf(ilo.y);
        vi[2] = (short)f2bf(ilo.z); vi[3] = (short)f2bf(ilo.w);
        vi[4] = (short)f2bf(ihi.x); vi[5] = (short)f2bf(ihi.y);
        vi[6] = (short)f2bf(ihi.z); vi[7] = (short)f2bf(ihi.w);
        #pragma unroll
        for (int e = 0; e < 8; ++e) vn[e] = (short)(vi[e] ^ 0x8000);
        ar[kc] = vr; ai[kc] = vi; ain[kc] = vn;
    }

    #pragma unroll
    for (int nt = 0; nt < 8; ++nt) {
        f32x4 accR = {0.f, 0.f, 0.f, 0.f};
        f32x4 accI = {0.f, 0.f, 0.f, 0.f};
        #pragma unroll
        for (int kc = 0; kc < 4; ++kc) {
            const int kg = kc * 4 + kg4;
            bf16x8 br = Ur[kg * NDIM + nt * 16 + r15];
            bf16x8 bi = Ui[kg * NDIM + nt * 16 + r15];
            accR = __builtin_amdgcn_mfma_f32_16x16x32_bf16(ar[kc],  br, accR, 0, 0, 0);
            accR = __builtin_amdgcn_mfma_f32_16x16x32_bf16(ain[kc], bi, accR, 0, 0, 0);
            accI = __builtin_amdgcn_mfma_f32_16x16x32_bf16(ar[kc],  bi, accI, 0, 0, 0);
            accI = __builtin_amdgcn_mfma_f32_16x16x32_bf16(ai[kc],  br, accI, 0, 0, 0);
        }
        const int n    = nt * 16 + r15;
        const int brow = btile + kg4 * 4;
        #pragma unroll
        for (int r = 0; r < 4; ++r)
            outp[(size_t)(brow + r) * NDIM + n] = make_ushort2(f2bf(accR[r]), f2bf(accI[r]));
    }
}

extern "C" void kernel_launch(void* const* d_in, const int* in_sizes, int n_in,
                              void* d_out, int out_size, void* d_ws, size_t ws_size,
                              hipStream_t stream) {
    const float* xr  = (const float*)d_in[0];
    const float* xi  = (const float*)d_in[1];
    const float* mzi = (const float*)d_in[2];
    const float* oph = (const float*)d_in[3];

    build_scan<<<dim3(4, NCHUNK), dim3(256), 0, stream>>>(mzi);
    compose_quad<<<dim3(32, 4), dim3(256), 0, stream>>>();
    compose_final4<<<dim3(32), dim3(256), 0, stream>>>(oph);
    if (out_size == BDIM * NDIM) {
        cmatmul0<<<dim3(BDIM / 64), dim3(256), 0, stream>>>(xr, xi, (float*)d_out);
    } else {
        cmatmul1<<<dim3(BDIM / 64), dim3(256), 0, stream>>>(xr, xi, (ushort2*)d_out);
    }
}